// Round 1
// 141.006 us; speedup vs baseline: 1.0342x; 1.0342x over previous
//
#include <hip/hip_runtime.h>

#define EPS 1e-7f
#define BATCH 8
#define NPT 2048   // points per batch
#define NFEAT 6
#define LOG2E 1.44269504088896340736f
#define RPB 8      // rows per block

typedef float vf4 __attribute__((ext_vector_type(4)));

// Single fused kernel. Each block handles RPB consecutive rows (b, n0..n0+7).
// Every block loads ALL 2048 columns of its batch anyway, so it redundantly
// computes pow = momentum^(2*alpha) for the whole batch (4 values/thread),
// stages it in LDS, and block-reduces the batch min — no precompute kernel,
// no workspace, no inter-kernel dependency.
//
// R1 A/B: nontemporal store -> REGULAR store. Theory: dur_us = harness
// re-poison fill (~86us) + kernel (~60us). Kernel writes 134MB at only
// 2.2 TB/s while the fill hits 6.2 TB/s on the same buffer; every 64B line
// is fully written by 4 lanes so regular stores write-combine in L2 at full
// burst width — the nt bypass is the prime suspect for the 2.8x write gap.
__global__ __launch_bounds__(512)
void wij_fused_kernel(const float* __restrict__ emb,
                      const float* __restrict__ alpha,
                      const float* __restrict__ beta,
                      const float* __restrict__ radius,
                      float* __restrict__ out) {
    __shared__ float spow[NPT];   // pow row for this batch
    __shared__ float sred[8];     // per-wave mins

    int blk = blockIdx.x;                      // 0 .. BATCH*NPT/RPB - 1
    int b  = blk >> 8;                         // / (NPT/RPB) = /256
    int n0 = (blk & 255) * RPB;

    const float* base = emb + (size_t)b * NFEAT * NPT;
    int t = threadIdx.x;

    // ---- pow + min (redundant per block, trivial cost) ----
    float a2 = 2.0f * alpha[0];
    vf4 pm = ((const vf4*)(base + 4 * NPT))[t];
    vf4 pw;
    pw.x = __builtin_amdgcn_exp2f(a2 * __log2f(pm.x));
    pw.y = __builtin_amdgcn_exp2f(a2 * __log2f(pm.y));
    pw.z = __builtin_amdgcn_exp2f(a2 * __log2f(pm.z));
    pw.w = __builtin_amdgcn_exp2f(a2 * __log2f(pm.w));
    ((vf4*)spow)[t] = pw;

    float lmin = fminf(fminf(pw.x, pw.y), fminf(pw.z, pw.w));
    for (int off = 32; off > 0; off >>= 1)
        lmin = fminf(lmin, __shfl_down(lmin, off, 64));
    if ((t & 63) == 0) sred[t >> 6] = lmin;
    __syncthreads();
    float dmin = fminf(fminf(fminf(sred[0], sred[1]), fminf(sred[2], sred[3])),
                       fminf(fminf(sred[4], sred[5]), fminf(sred[6], sred[7]))) + EPS;

    // ---- fold scalars: w = exp2(beff2 - cb * |c_n-c_m|^2 * min(pn,pm)) ----
    float r  = radius[0];
    float bt = beta[0];
    float beff2 = bt * bt * 1e-4f * LOG2E;           // beta^2/1e4 in base-2
    float cb = beff2 / (dmin * (r * r + EPS));       // one divide per thread, off hot path

    // ---- column fragments ----
    vf4 cx = ((const vf4*)(base + 1 * NPT))[t];
    vf4 cy = ((const vf4*)(base + 2 * NPT))[t];

    // ---- row scalars ----
    float xn[RPB], yn[RPB], pn[RPB];
    #pragma unroll
    for (int rI = 0; rI < RPB; ++rI) {
        xn[rI] = base[1 * NPT + n0 + rI];
        yn[rI] = base[2 * NPT + n0 + rI];
        pn[rI] = spow[n0 + rI];
    }

    vf4* outp = (vf4*)(out + (size_t)(b * NPT + n0) * NPT) + t;
    #pragma unroll
    for (int rI = 0; rI < RPB; ++rI) {
        vf4 w;
        {
            float dx = xn[rI] - cx.x, dy = yn[rI] - cy.x;
            float da = (dx * dx + dy * dy) * fminf(pn[rI], pw.x);
            w.x = __builtin_amdgcn_exp2f(beff2 - cb * da);
        }
        {
            float dx = xn[rI] - cx.y, dy = yn[rI] - cy.y;
            float da = (dx * dx + dy * dy) * fminf(pn[rI], pw.y);
            w.y = __builtin_amdgcn_exp2f(beff2 - cb * da);
        }
        {
            float dx = xn[rI] - cx.z, dy = yn[rI] - cy.z;
            float da = (dx * dx + dy * dy) * fminf(pn[rI], pw.z);
            w.z = __builtin_amdgcn_exp2f(beff2 - cb * da);
        }
        {
            float dx = xn[rI] - cx.w, dy = yn[rI] - cy.w;
            float da = (dx * dx + dy * dy) * fminf(pn[rI], pw.w);
            w.w = __builtin_amdgcn_exp2f(beff2 - cb * da);
        }
        // regular (cached) store — full 64B lines, L2 write-combine path
        outp[(size_t)rI * (NPT / 4)] = w;
    }
}

extern "C" void kernel_launch(void* const* d_in, const int* in_sizes, int n_in,
                              void* d_out, int out_size, void* d_ws, size_t ws_size,
                              hipStream_t stream) {
    const float* emb    = (const float*)d_in[0];
    const float* alpha  = (const float*)d_in[1];
    const float* beta   = (const float*)d_in[2];
    const float* radius = (const float*)d_in[3];
    float* out = (float*)d_out;
    (void)d_ws; (void)ws_size;

    wij_fused_kernel<<<(BATCH * NPT) / RPB, 512, 0, stream>>>(emb, alpha, beta, radius, out);
}